// Round 21
// baseline (373.085 us; speedup 1.0000x reference)
//
#include <hip/hip_runtime.h>

#define N1V 100000
#define N2V 500
#define NEV 1000000
#define ALPHAV 0.2f
#define NB 2048       // histogram/scatter blocks
#define CHUNK 489     // ceil(NEV/NB)
#define CHD 8         // dst chunks per type
#define NDSTB (N2V * CHD)          // 4000 dst blocks
#define NSRCB (N1V / 4)            // 25000 src blocks
#define NGEMM1 ((N1V + 63) / 64)   // 1563
#define NGEMM2 ((N2V + 63) / 64)   // 8

typedef float f32x4 __attribute__((ext_vector_type(4)));
typedef unsigned int u32;
typedef unsigned short u16;
typedef u32 u32x2 __attribute__((ext_vector_type(2)));
using bf16x8 = __attribute__((ext_vector_type(8))) short;   // 8 bf16 (4 VGPRs)
using f32x4v = __attribute__((ext_vector_type(4))) float;

__device__ __forceinline__ u32 pack_bf16x2(float a, float b) {
  u32 ua = __float_as_uint(a), ub = __float_as_uint(b);
  u32 ra = (ua + 0x7FFFu + ((ua >> 16) & 1u)) >> 16;
  u32 rb = (ub + 0x7FFFu + ((ub >> 16) & 1u)) >> 16;
  return ra | (rb << 16);
}

__device__ __forceinline__ float bf16_lo(u32 v) { return __uint_as_float(v << 16); }
__device__ __forceinline__ float bf16_hi(u32 v) { return __uint_as_float(v & 0xFFFF0000u); }

// ---------------- prep: c[320] = a^T @ a_2 ----------------
__global__ __launch_bounds__(256) void k_prep(const float* __restrict__ a,
                                              const float* __restrict__ a2,
                                              float* __restrict__ c) {
  int p = blockIdx.x * 256 + threadIdx.x;
  if (p < 320) {
    float s = 0.f;
    for (int k = 0; k < 128; ++k) s += a2[k] * a[k * 320 + p];
    c[p] = s;
  }
}

// ---------------- fused bf16 conversions + z1/z2 dots ----------------
__global__ __launch_bounds__(256) void k_conv(const float* __restrict__ x1,
                                              const float* __restrict__ x2,
                                              const float* __restrict__ a,
                                              const float* __restrict__ c,
                                              u32* __restrict__ x1bf,
                                              u32* __restrict__ x2bf,
                                              u32* __restrict__ abf,
                                              float* __restrict__ z1g,
                                              float* __restrict__ z2g) {
  size_t gid = (size_t)blockIdx.x * 256 + threadIdx.x;
  const size_t n_x1 = (size_t)N1V * 16;        // 1,600,000 (64-aligned)
  const size_t n_a = 128 * 320 / 8;            // 5,120 (64-aligned)
  const size_t n_x2 = (size_t)N2V * 16;        // 8,000
  if (gid < n_x1) {
    size_t row = gid >> 4; int chunk = (int)(gid & 15);
    const f32x4* s = (const f32x4*)(x1 + row * 128 + chunk * 8);
    f32x4 v0 = s[0], v1 = s[1];
    uint4 o;
    o.x = pack_bf16x2(v0.x, v0.y); o.y = pack_bf16x2(v0.z, v0.w);
    o.z = pack_bf16x2(v1.x, v1.y); o.w = pack_bf16x2(v1.z, v1.w);
    *(uint4*)(x1bf + row * 64 + chunk * 4) = o;
    const float* cp = c + chunk * 8;
    float d = v0.x * cp[0] + v0.y * cp[1] + v0.z * cp[2] + v0.w * cp[3] +
              v1.x * cp[4] + v1.y * cp[5] + v1.z * cp[6] + v1.w * cp[7];
#pragma unroll
    for (int off = 1; off < 16; off <<= 1) d += __shfl_xor(d, off, 64);
    if (chunk == 0) z1g[row] = d;
  } else if (gid < n_x1 + n_a) {
    size_t idx = gid - n_x1;
    const f32x4* s = (const f32x4*)(a + idx * 8);
    f32x4 v0 = s[0], v1 = s[1];
    uint4 o;
    o.x = pack_bf16x2(v0.x, v0.y); o.y = pack_bf16x2(v0.z, v0.w);
    o.z = pack_bf16x2(v1.x, v1.y); o.w = pack_bf16x2(v1.z, v1.w);
    *(uint4*)(abf + idx * 4) = o;
  } else if (gid < n_x1 + n_a + n_x2) {
    size_t idx = gid - n_x1 - n_a;
    size_t row = idx >> 4; int chunk = (int)(idx & 15);
    const f32x4* s = (const f32x4*)(x2 + row * 128 + chunk * 8);
    f32x4 v0 = s[0], v1 = s[1];
    uint4 o;
    o.x = pack_bf16x2(v0.x, v0.y); o.y = pack_bf16x2(v0.z, v0.w);
    o.z = pack_bf16x2(v1.x, v1.y); o.w = pack_bf16x2(v1.z, v1.w);
    *(uint4*)(x2bf + row * 64 + chunk * 4) = o;
    const float* cp = c + 128 + chunk * 8;
    float d = v0.x * cp[0] + v0.y * cp[1] + v0.z * cp[2] + v0.w * cp[3] +
              v1.x * cp[4] + v1.y * cp[5] + v1.z * cp[6] + v1.w * cp[7];
#pragma unroll
    for (int off = 1; off < 16; off <<= 1) d += __shfl_xor(d, off, 64);
    if (chunk == 0) z2g[row] = d;
  }
}

// ---------------- linear pass: histograms + w + bf16 transcode (register-direct) ----------------
__global__ __launch_bounds__(256) void k_histw(const int* __restrict__ src,
                                               const int* __restrict__ dst,
                                               const float* __restrict__ ee,
                                               const float* __restrict__ z1g,
                                               const float* __restrict__ z2g,
                                               const float* __restrict__ c,
                                               int* __restrict__ c1,
                                               int* __restrict__ hblk,
                                               float* __restrict__ wbuf,
                                               u32* __restrict__ eeh) {
  __shared__ int h[512];
  for (int i = threadIdx.x; i < 512; i += 256) h[i] = 0;
  int tid = threadIdx.x;
  int wave = tid >> 6, lane = tid & 63;
  int r = lane >> 4, cc = lane & 15;
  float c0 = c[256 + cc * 4 + 0], c1r = c[256 + cc * 4 + 1];
  float c2 = c[256 + cc * 4 + 2], c3 = c[256 + cc * 4 + 3];
  __syncthreads();

  int b = blockIdx.x;
  int b0 = b * CHUNK, b1 = min(b0 + CHUNK, NEV);
  for (int eb = b0 + wave * 4; eb < b1; eb += 16) {
    int e = eb + r;
    bool ok = e < b1;
    int ec = ok ? e : b0;
    f32x4 v = __builtin_nontemporal_load((const f32x4*)(ee + (size_t)ec * 64) + cc);
    float d = v.x * c0 + v.y * c1r + v.z * c2 + v.w * c3;
#pragma unroll
    for (int off = 1; off < 16; off <<= 1) d += __shfl_xor(d, off, 64);
    if (ok) {
      u32x2 o;
      o.x = pack_bf16x2(v.x, v.y);
      o.y = pack_bf16x2(v.z, v.w);
      *(u32x2*)(eeh + (size_t)ec * 32 + cc * 2) = o;
      if (cc == 0) {
        int sv = src[e], dv = dst[e];
        float z = z1g[sv] + z2g[dv] + d;
        float zp = z > 0.f ? z : ALPHAV * z;
        wbuf[e] = __expf(-zp);
        atomicAdd(&c1[sv], 1);
        atomicAdd(&h[dv], 1);
      }
    }
  }
  __syncthreads();
  for (int i = threadIdx.x; i < 512; i += 256) hblk[(size_t)b * 512 + i] = h[i];
}

// ---------------- column scan over NB blocks ----------------
__global__ __launch_bounds__(256) void k_colscan(int* __restrict__ hblk,
                                                 int* __restrict__ tot2) {
  __shared__ int s[256];
  int t = blockIdx.x;
  int tid = threadIdx.x;
  int v[8]; int tot = 0;
#pragma unroll
  for (int j = 0; j < 8; ++j) {
    int b = tid * 8 + j;
    v[j] = hblk[(size_t)b * 512 + t];
    tot += v[j];
  }
  s[tid] = tot; __syncthreads();
  for (int off = 1; off < 256; off <<= 1) {
    int tv = (tid >= off) ? s[tid - off] : 0;
    __syncthreads();
    if (tid >= off) s[tid] += tv;
    __syncthreads();
  }
  int run = s[tid] - tot;
#pragma unroll
  for (int j = 0; j < 8; ++j) {
    int b = tid * 8 + j;
    hblk[(size_t)b * 512 + t] = run;
    run += v[j];
  }
  if (tid == 255) tot2[t] = run;
}

// ---------------- scan for src counts ----------------
__global__ __launch_bounds__(256) void k_scanA(const int* __restrict__ cnt,
                                               int* __restrict__ outp,
                                               int* __restrict__ partials, int n) {
  __shared__ int s[256];
  int tid = threadIdx.x;
  int base = blockIdx.x * 2048 + tid * 8;
  int v[8]; int tot = 0;
#pragma unroll
  for (int j = 0; j < 8; ++j) { int idx = base + j; v[j] = (idx < n) ? cnt[idx] : 0; tot += v[j]; }
  s[tid] = tot; __syncthreads();
  for (int off = 1; off < 256; off <<= 1) {
    int tv = 0;
    if (tid >= off) tv = s[tid - off];
    __syncthreads();
    if (tid >= off) s[tid] += tv;
    __syncthreads();
  }
  int run = s[tid] - tot;
#pragma unroll
  for (int j = 0; j < 8; ++j) { int idx = base + j; if (idx < n) outp[idx] = run; run += v[j]; }
  if (tid == 255) partials[blockIdx.x] = s[255];
}

__global__ __launch_bounds__(512) void k_scanB(int* __restrict__ partials, int nPart,
                                               const int* __restrict__ tot2,
                                               int* __restrict__ rp2) {
  __shared__ int s[512];
  int tid = threadIdx.x;
  int v = (tid < N2V) ? tot2[tid] : 0;
  s[tid] = v; __syncthreads();
  for (int off = 1; off < 512; off <<= 1) {
    int tv = 0;
    if (tid >= off) tv = s[tid - off];
    __syncthreads();
    if (tid >= off) s[tid] += tv;
    __syncthreads();
  }
  if (tid < N2V) rp2[tid] = s[tid] - v;
  if (tid == N2V - 1) rp2[N2V] = s[tid];
  if (tid == 0) {
    int run = 0;
    for (int b = 0; b < nPart; ++b) { int t = partials[b]; partials[b] = run; run += t; }
  }
}

__global__ __launch_bounds__(256) void k_scanC(int* __restrict__ rp, int* __restrict__ cur,
                                               const int* __restrict__ partials, int n, int total) {
  int i = blockIdx.x * 256 + threadIdx.x;
  if (i < n) {
    int v = rp[i] + partials[i >> 11];
    rp[i] = v; cur[i] = v;
  }
  if (i == 0) rp[n] = total;
}

// ---------------- scatter: CSR placement, one 16B record per slot ----------------
__global__ __launch_bounds__(256) void k_scatter(const int* __restrict__ src,
                                                 const int* __restrict__ dst,
                                                 const float* __restrict__ wbuf,
                                                 int* __restrict__ cur1,
                                                 const int* __restrict__ hblk,
                                                 const int* __restrict__ rp2,
                                                 uint4* __restrict__ rec1,
                                                 uint4* __restrict__ rec2) {
  __shared__ int h[512];
  __shared__ int basep[512];
  int b = blockIdx.x;
  int b0 = b * CHUNK, b1 = min(b0 + CHUNK, NEV);
  for (int i = threadIdx.x; i < 512; i += 256) {
    basep[i] = ((i < N2V) ? rp2[i] : 0) + hblk[(size_t)b * 512 + i];
    h[i] = 0;
  }
  __syncthreads();
  for (int e = b0 + threadIdx.x; e < b1; e += 256) {
    int sv = src[e], d = dst[e];
    u32 wbits = __float_as_uint(wbuf[e]);
    int p = atomicAdd(&cur1[sv], 1);
    uint4 r1; r1.x = (u32)e; r1.y = wbits; r1.z = (u32)d; r1.w = 0;
    rec1[p] = r1;
    int loc = atomicAdd(&h[d], 1);
    uint4 r2; r2.x = (u32)e; r2.y = wbits; r2.z = (u32)sv; r2.w = 0;
    rec2[basep[d] + loc] = r2;
  }
}

// ---------------- fused gather pass (bf16 rows, 16B slot records) ----------------
__global__ __launch_bounds__(256) void k_gather(const u32* __restrict__ x1bf,
                                                const u32* __restrict__ x2bf,
                                                const u32* __restrict__ eeh32,
                                                const int* __restrict__ rp2,
                                                const uint4* __restrict__ rec2,
                                                const int* __restrict__ rp1,
                                                const uint4* __restrict__ rec1,
                                                float* __restrict__ acc2,
                                                u32* __restrict__ sbuf1bf,
                                                float* __restrict__ rs1) {
  __shared__ float red[4][224];
  int tid = threadIdx.x;
  int l = tid & 63;
  int pl = l & 31, hi = l >> 5;

  if (blockIdx.x < NDSTB) {
    // ---------- dst role ----------
    int t = blockIdx.x / CHD;
    int chunk = blockIdx.x % CHD;
    int wv = tid >> 6;
    int start = rp2[t], end = rp2[t + 1];
    int n = end - start;
    int sub = chunk * 4 + wv;                                  // 0..31
    int i0 = start + (int)(((long long)n * sub) >> 5);
    int i1 = start + (int)(((long long)n * (sub + 1)) >> 5);
    float sxaa = 0.f, sxab = 0.f, sxba = 0.f, sxbb = 0.f, s3a = 0.f, s3b = 0.f, rsum = 0.f;
    int p = i0;
    for (; p + 4 <= i1; p += 4) {
      uint4 ra = rec2[p + hi], rb = rec2[p + 2 + hi];
      int ea = (int)ra.x, eb = (int)rb.x;
      float wa = __uint_as_float(ra.y), wb = __uint_as_float(rb.y);
      int sa = (int)ra.z, sb = (int)rb.z;
      u32 va = eeh32[(size_t)ea * 32 + pl];
      u32 vb = eeh32[(size_t)eb * 32 + pl];
      u32 xaa = x1bf[(size_t)sa * 64 + pl];
      u32 xab = x1bf[(size_t)sa * 64 + 32 + pl];
      u32 xba = x1bf[(size_t)sb * 64 + pl];
      u32 xbb = x1bf[(size_t)sb * 64 + 32 + pl];
      rsum += wa + wb;
      s3a += wa * bf16_lo(va) + wb * bf16_lo(vb);
      s3b += wa * bf16_hi(va) + wb * bf16_hi(vb);
      sxaa += wa * bf16_lo(xaa) + wb * bf16_lo(xba);
      sxab += wa * bf16_hi(xaa) + wb * bf16_hi(xba);
      sxba += wa * bf16_lo(xab) + wb * bf16_lo(xbb);
      sxbb += wa * bf16_hi(xab) + wb * bf16_hi(xbb);
    }
    for (; p < i1; p += 2) {
      int q = p + hi;
      bool ok = q < i1;
      uint4 ra = rec2[ok ? q : i0];
      int ea = (int)ra.x;
      float wa = ok ? __uint_as_float(ra.y) : 0.f;
      int sa = (int)ra.z;
      u32 va = eeh32[(size_t)ea * 32 + pl];
      u32 xaa = x1bf[(size_t)sa * 64 + pl];
      u32 xab = x1bf[(size_t)sa * 64 + 32 + pl];
      rsum += wa;
      s3a += wa * bf16_lo(va);
      s3b += wa * bf16_hi(va);
      sxaa += wa * bf16_lo(xaa); sxab += wa * bf16_hi(xaa);
      sxba += wa * bf16_lo(xab); sxbb += wa * bf16_hi(xab);
    }
    sxaa += __shfl_xor(sxaa, 32); sxab += __shfl_xor(sxab, 32);
    sxba += __shfl_xor(sxba, 32); sxbb += __shfl_xor(sxbb, 32);
    s3a += __shfl_xor(s3a, 32);  s3b += __shfl_xor(s3b, 32);
    rsum += __shfl_xor(rsum, 32);
    if (hi == 0) {
      red[wv][2 * pl] = sxaa;       red[wv][2 * pl + 1] = sxab;
      red[wv][64 + 2 * pl] = sxba;  red[wv][64 + 2 * pl + 1] = sxbb;
      red[wv][128 + 2 * pl] = s3a;  red[wv][128 + 2 * pl + 1] = s3b;
      if (pl == 0) red[wv][192] = rsum;
    }
    __syncthreads();
    if (tid < 193) {
      float v = red[0][tid] + red[1][tid] + red[2][tid] + red[3][tid];
      if (v != 0.f) atomicAdd(&acc2[t * 256 + tid], v);
    }
  } else {
    // ---------- src role ----------
    int bid = blockIdx.x - NDSTB;
    int wid = (bid * 256 + tid) >> 6;
    if (wid >= N1V) return;
    int start = rp1[wid], end = rp1[wid + 1];
    float s2aa = 0.f, s2ab = 0.f, s2ba = 0.f, s2bb = 0.f, s1a = 0.f, s1b = 0.f, rsum = 0.f;
    int p = start;
    for (; p + 4 <= end; p += 4) {
      uint4 ra = rec1[p + hi], rb = rec1[p + 2 + hi];
      int ea = (int)ra.x, eb = (int)rb.x;
      float wa = __uint_as_float(ra.y), wb = __uint_as_float(rb.y);
      int da = (int)ra.z, db = (int)rb.z;
      u32 va = eeh32[(size_t)ea * 32 + pl];
      u32 vb = eeh32[(size_t)eb * 32 + pl];
      u32 xaa = x2bf[(size_t)da * 64 + pl];
      u32 xab = x2bf[(size_t)da * 64 + 32 + pl];
      u32 xba = x2bf[(size_t)db * 64 + pl];
      u32 xbb = x2bf[(size_t)db * 64 + 32 + pl];
      rsum += wa + wb;
      s1a += wa * bf16_lo(va) + wb * bf16_lo(vb);
      s1b += wa * bf16_hi(va) + wb * bf16_hi(vb);
      s2aa += wa * bf16_lo(xaa) + wb * bf16_lo(xba);
      s2ab += wa * bf16_hi(xaa) + wb * bf16_hi(xba);
      s2ba += wa * bf16_lo(xab) + wb * bf16_lo(xbb);
      s2bb += wa * bf16_hi(xab) + wb * bf16_hi(xbb);
    }
    for (; p < end; p += 2) {
      int q = p + hi;
      bool ok = q < end;
      uint4 ra = rec1[ok ? q : start];
      int ea = (int)ra.x;
      float wa = ok ? __uint_as_float(ra.y) : 0.f;
      int da = (int)ra.z;
      u32 va = eeh32[(size_t)ea * 32 + pl];
      u32 xaa = x2bf[(size_t)da * 64 + pl];
      u32 xab = x2bf[(size_t)da * 64 + 32 + pl];
      rsum += wa;
      s1a += wa * bf16_lo(va);
      s1b += wa * bf16_hi(va);
      s2aa += wa * bf16_lo(xaa); s2ab += wa * bf16_hi(xaa);
      s2ba += wa * bf16_lo(xab); s2bb += wa * bf16_hi(xab);
    }
    s2aa += __shfl_xor(s2aa, 32); s2ab += __shfl_xor(s2ab, 32);
    s2ba += __shfl_xor(s2ba, 32); s2bb += __shfl_xor(s2bb, 32);
    s1a += __shfl_xor(s1a, 32);  s1b += __shfl_xor(s1b, 32);
    rsum += __shfl_xor(rsum, 32);
    float scale = (end > start) ? 1.0f / rsum : 0.f;
    if (hi == 0) {
      u32* baseo = sbuf1bf + (size_t)wid * 96;
      baseo[pl] = pack_bf16x2(s2aa * scale, s2ab * scale);
      baseo[32 + pl] = pack_bf16x2(s2ba * scale, s2bb * scale);
      baseo[64 + pl] = pack_bf16x2(s1a * scale, s1b * scale);
      if (pl == 0) rs1[wid] = (end > start) ? rsum : 0.f;
    }
  }
}

// ---------------- dst finalize: bf16-pack sbuf2 ----------------
__global__ __launch_bounds__(256) void k_dst_final(const float* __restrict__ acc2,
                                                   u32* __restrict__ sbuf2bf,
                                                   float* __restrict__ rs2) {
  int t = blockIdx.x, tid = threadIdx.x;
  float rtot = acc2[t * 256 + 192];
  float scale = rtot > 0.f ? 1.0f / rtot : 0.f;
  if (tid < 192) {
    float o = acc2[t * 256 + tid] * scale;
    float pr = __shfl_xor(o, 1);
    if (!(tid & 1)) sbuf2bf[t * 96 + (tid >> 1)] = pack_bf16x2(o, pr);
  }
  if (tid == 192) rs2[t] = rtot;
}

// ---------------- MFMA output GEMM, both modes in one launch ----------------
__global__ __launch_bounds__(256) void k_gemm(const u32* __restrict__ x1bf,
                                              const u32* __restrict__ sbuf1bf,
                                              const u32* __restrict__ x2bf,
                                              const u32* __restrict__ sbuf2bf,
                                              const u32* __restrict__ abf,   // [128][160] u32
                                              const float* __restrict__ rs1,
                                              const float* __restrict__ rs2,
                                              float* __restrict__ outall) {
  __shared__ short Bt[128 * 40];   // [n=128][k=32 bf16 + pad 8]
  int tid = threadIdx.x;
  int w = tid >> 6, l = tid & 63;
  int r = l & 15, cchunk = l >> 4;          // 0..3
  int mode, row0, M;
  const u32 *Xbf, *Sbf;
  const float* rs;
  float* out;
  if (blockIdx.x < NGEMM1) {
    mode = 0; row0 = blockIdx.x * 64; M = N1V;
    Xbf = x1bf; Sbf = sbuf1bf; rs = rs1; out = outall;
  } else {
    mode = 1; row0 = (blockIdx.x - NGEMM1) * 64; M = N2V;
    Xbf = x2bf; Sbf = sbuf2bf; rs = rs2; out = outall + (size_t)N1V * 128;
  }
  int gi = row0 + w * 16 + r;               // A-row this lane loads
  int gclamp = min(gi, M - 1);
  f32x4v acc[8];
#pragma unroll
  for (int i = 0; i < 8; ++i) acc[i] = (f32x4v){0.f, 0.f, 0.f, 0.f};

  for (int ks = 0; ks < 10; ++ks) {
    if (ks) __syncthreads();
    {
      int n = tid >> 1, half = tid & 1;
      const u32* srcp = abf + n * 160 + ks * 16 + half * 8;
      u32* dstp = (u32*)&Bt[n * 40] + half * 8;
      *(uint4*)(dstp) = *(const uint4*)(srcp);
      *(uint4*)(dstp + 4) = *(const uint4*)(srcp + 4);
    }
    __syncthreads();
    int ck = ks * 4 + cchunk;                // 8-elem chunk index, 0..39
    const u32* ap;
    if (mode == 0) {
      ap = (ck < 16) ? (Xbf + (size_t)gclamp * 64 + ck * 4)
                     : (Sbf + (size_t)gclamp * 96 + (ck - 16) * 4);
    } else {
      ap = (ck < 16) ? (Sbf + (size_t)gclamp * 96 + ck * 4)
         : (ck < 32) ? (Xbf + (size_t)gclamp * 64 + (ck - 16) * 4)
                     : (Sbf + (size_t)gclamp * 96 + 64 + (ck - 32) * 4);
    }
    bf16x8 afrag = *(const bf16x8*)ap;
#pragma unroll
    for (int nt = 0; nt < 8; ++nt) {
      bf16x8 bfrag = *(const bf16x8*)&Bt[(nt * 16 + r) * 40 + cchunk * 8];
      acc[nt] = __builtin_amdgcn_mfma_f32_16x16x32_bf16(afrag, bfrag, acc[nt], 0, 0, 0);
    }
  }
  int baser = row0 + w * 16 + cchunk * 4;
#pragma unroll
  for (int rr = 0; rr < 4; ++rr) {
    int go = baser + rr;
    if (go < M) {
      float rsv = rs[go];
      bool ok = rsv > 0.f;
#pragma unroll
      for (int nt = 0; nt < 8; ++nt) {
        float h = acc[nt][rr];
        float v = ok ? (h > 0.f ? h : expm1f(h)) : 0.f;
        out[(size_t)go * 128 + nt * 16 + r] = v;
      }
    }
  }
}

// =====================================================================================

static inline size_t align_up(size_t x, size_t a) { return (x + a - 1) & ~(a - 1); }

extern "C" void kernel_launch(void* const* d_in, const int* in_sizes, int n_in,
                              void* d_out, int out_size, void* d_ws, size_t ws_size,
                              hipStream_t stream) {
  const float* x1 = (const float*)d_in[0];
  const float* x2 = (const float*)d_in[1];
  const float* ee = (const float*)d_in[2];
  const float* a = (const float*)d_in[3];
  const float* a2 = (const float*)d_in[4];
  const int* esrc = (const int*)d_in[5];
  const int* edst = (const int*)d_in[6];
  float* out = (float*)d_out;

  char* base = (char*)d_ws;
  size_t off = 0;
  auto alloc = [&](size_t bytes) -> char* {
    char* p = base + off;
    off = align_up(off + bytes, 256);
    return p;
  };
  float* c = (float*)alloc(320 * 4);
  float* z1g = (float*)alloc(N1V * 4);
  float* z2g = (float*)alloc(512 * 4);
  u32* x1bf = (u32*)alloc((size_t)N1V * 64 * 4);      // 25.6 MB
  u32* x2bf = (u32*)alloc((size_t)N2V * 64 * 4);
  u32* abf = (u32*)alloc(128 * 160 * 4);              // 80 KB
  int* rp1 = (int*)alloc((N1V + 1) * 4);
  int* cur1 = (int*)alloc(N1V * 4);
  int* rp2 = (int*)alloc(512 * 4);
  int* partials = (int*)alloc(64 * 4);
  int* hblk = (int*)alloc((size_t)NB * 512 * 4);      // 4 MB
  int* tot2 = (int*)alloc(512 * 4);
  uint4* rec1 = (uint4*)alloc((size_t)NEV * 16);      // 16 MB
  uint4* rec2 = (uint4*)alloc((size_t)NEV * 16);      // 16 MB
  float* wbuf = (float*)alloc(NEV * 4);
  u32* eeh = (u32*)alloc((size_t)NEV * 128);          // 128 MB (bf16 ee)
  float* rs1 = (float*)alloc(N1V * 4);
  float* rs2 = (float*)alloc(512 * 4);
  u32* sbuf1bf = (u32*)alloc((size_t)N1V * 96 * 4);   // 38.4 MB
  u32* sbuf2bf = (u32*)alloc(512 * 96 * 4);
  float* acc2 = (float*)alloc(512 * 256 * 4);
  (void)ws_size; (void)out_size; (void)n_in; (void)in_sizes;

  hipMemsetAsync(cur1, 0, N1V * 4, stream);
  hipMemsetAsync(acc2, 0, 512 * 256 * 4, stream);

  hipLaunchKernelGGL(k_prep, dim3(2), dim3(256), 0, stream, a, a2, c);
  hipLaunchKernelGGL(k_conv, dim3((1600000 + 5120 + 8000 + 255) / 256), dim3(256), 0, stream,
                     x1, x2, a, c, x1bf, x2bf, abf, z1g, z2g);
  hipLaunchKernelGGL(k_histw, dim3(NB), dim3(256), 0, stream,
                     esrc, edst, ee, z1g, z2g, c, cur1, hblk, wbuf, eeh);
  hipLaunchKernelGGL(k_colscan, dim3(512), dim3(256), 0, stream, hblk, tot2);

  const int nScanBlocks = (N1V + 2047) / 2048;  // 49
  hipLaunchKernelGGL(k_scanA, dim3(nScanBlocks), dim3(256), 0, stream, cur1, rp1, partials, N1V);
  hipLaunchKernelGGL(k_scanB, dim3(1), dim3(512), 0, stream, partials, nScanBlocks, tot2, rp2);
  hipLaunchKernelGGL(k_scanC, dim3((N1V + 255) / 256), dim3(256), 0, stream, rp1, cur1, partials, N1V, NEV);
  hipLaunchKernelGGL(k_scatter, dim3(NB), dim3(256), 0, stream,
                     esrc, edst, wbuf, cur1, hblk, rp2, rec1, rec2);

  hipLaunchKernelGGL(k_gather, dim3(NDSTB + NSRCB), dim3(256), 0, stream,
                     x1bf, x2bf, eeh, rp2, rec2, rp1, rec1,
                     acc2, sbuf1bf, rs1);
  hipLaunchKernelGGL(k_dst_final, dim3(N2V), dim3(256), 0, stream, acc2, sbuf2bf, rs2);

  hipLaunchKernelGGL(k_gemm, dim3(NGEMM1 + NGEMM2), dim3(256), 0, stream,
                     x1bf, sbuf1bf, x2bf, sbuf2bf, abf, rs1, rs2, out);
}